// Round 5
// baseline (157.679 us; speedup 1.0000x reference)
//
#include <hip/hip_runtime.h>
#include <hip/hip_bf16.h>

#define D 512
#define NWAY 64
#define KSHOT 16
#define NQ 8192

typedef __bf16 bf16_t;
typedef __bf16 bf16x8_t __attribute__((ext_vector_type(8)));
typedef float  f32x4    __attribute__((ext_vector_type(4)));

typedef __attribute__((address_space(1))) const void gv_t;
typedef __attribute__((address_space(3))) void lv_t;
__device__ __forceinline__ void ld16(const void* g, void* l) {
    __builtin_amdgcn_global_load_lds((gv_t*)g, (lv_t*)l, 16, 0, 0);
}

// Global pre-swizzled layouts (bf16 elems; 8-elem = 16 B segments):
//  Aq: [rt(256)][ck(8)][m(32)][seg(8)]  elem off = rt*16384 + ck*2048 + m*64 + ((s^(m&7))*8)
//      holds query[rt*32+m][ck*64 + s*8 .. +8]
//  Bsw:[ck(8)][n(576)][seg(8)]          elem off = ck*36864 + n*64 + ((s^(n&7))*8)
//      rows 0..511 = W, rows 512..575 = G (G_c = W^T p_c)

// ---------------------------------------------------------------- K_PREP
// b<1024: query->bf16 swizzled | 1024..1279: W->bf16 swizzled | 1280..1343: class chains
__global__ __launch_bounds__(256) void k_prep(
    const float* __restrict__ sup, const float* __restrict__ query,
    const float* __restrict__ W,   const float* __restrict__ bias,
    bf16_t* __restrict__ Aq, bf16_t* __restrict__ Bsw, float* __restrict__ ph)
{
    const int b = blockIdx.x, t = threadIdx.x;

    if (b < 1024) {                       // ---- query conversion, 8 rows/block
        const int r  = b * 8 + (t >> 5);
        const int m  = r & 31, rt = r >> 5;
        const int s2 = t & 31;
#pragma unroll
        for (int h = 0; h < 2; ++h) {
            const int sl = s2 + h * 32;                 // 0..63 seg of row
            const f32x4* qp = (const f32x4*)(query + (size_t)r * D + sl * 8);
            f32x4 v0 = qp[0], v1 = qp[1];
            bf16x8_t hv = { (bf16_t)v0[0], (bf16_t)v0[1], (bf16_t)v0[2], (bf16_t)v0[3],
                            (bf16_t)v1[0], (bf16_t)v1[1], (bf16_t)v1[2], (bf16_t)v1[3] };
            const int ck = sl >> 3, s = sl & 7;
            *(bf16x8_t*)(Aq + (size_t)rt * 16384 + ck * 2048 + m * 64 + ((s ^ (m & 7)) * 8)) = hv;
        }
        return;
    }

    if (b < 1280) {                       // ---- W conversion, 2 rows/block
        if (t < 128) {
            const int n = (b - 1024) * 2 + (t >> 6);
            const int sl = t & 63;
            const f32x4* wp = (const f32x4*)(W + (size_t)n * D + sl * 8);
            f32x4 v0 = wp[0], v1 = wp[1];
            bf16x8_t hv = { (bf16_t)v0[0], (bf16_t)v0[1], (bf16_t)v0[2], (bf16_t)v0[3],
                            (bf16_t)v1[0], (bf16_t)v1[1], (bf16_t)v1[2], (bf16_t)v1[3] };
            const int ck = sl >> 3, s = sl & 7;
            *(bf16x8_t*)(Bsw + (size_t)ck * 36864 + n * 64 + ((s ^ (n & 7)) * 8)) = hv;
        }
        return;
    }

    // ---- per-class chain: cm_c -> P_c -> G_c, ph_c
    const int c = b - 1280;
    __shared__ __align__(16) float cm[D];
    __shared__ __align__(16) float P[D];
    __shared__ float red[4];

    {   // cm_c
        const int d = t * 2;
        float sx = 0.f, sy = 0.f;
#pragma unroll
        for (int j = 0; j < KSHOT; ++j) {
            float2 v = *(const float2*)(sup + (size_t)(c * KSHOT + j) * D + d);
            sx += v.x; sy += v.y;
        }
        cm[d] = sx * (1.0f / KSHOT); cm[d + 1] = sy * (1.0f / KSHOT);
    }
    __syncthreads();

    {   // P_c[j] = cm . W_j + b_j
#pragma unroll
        for (int h = 0; h < 2; ++h) {
            const int j = t + h * 256;
            const f32x4* wr = (const f32x4*)(W + (size_t)j * D);
            const f32x4* cr = (const f32x4*)cm;
            float s = 0.f;
#pragma unroll 4
            for (int i = 0; i < 128; ++i) {
                f32x4 a = cr[i], wv = wr[i];
                s += a[0]*wv[0] + a[1]*wv[1] + a[2]*wv[2] + a[3]*wv[3];
            }
            P[j] = s + bias[j];
        }
    }
    __syncthreads();

    {   // G_c[k] = sum_j P[j] W[j][k]  -> Bsw row 512+c (swizzled bf16)
#pragma unroll
        for (int h = 0; h < 2; ++h) {
            const int k = t + h * 256;
            float g = 0.f;
            for (int j = 0; j < D; ++j) g += P[j] * W[(size_t)j * D + k];
            const int ck = k >> 6, s = (k >> 3) & 7, e = k & 7;
            Bsw[(size_t)ck * 36864 + (512 + c) * 64 + ((s ^ (c & 7)) * 8) + e] = (bf16_t)g;
        }
    }

    {   // ph_c = ||p||^2 - 2 b.p
        float pp = 0.f;
#pragma unroll
        for (int h = 0; h < 2; ++h) {
            const int j = t + h * 256;
            float v = P[j];
            pp += v * v - 2.0f * bias[j] * v;
        }
#pragma unroll
        for (int off = 32; off; off >>= 1) pp += __shfl_xor(pp, off);
        if ((t & 63) == 0) red[t >> 6] = pp;
        __syncthreads();
        if (t == 0) ph[c] = red[0] + red[1] + red[2] + red[3];
    }
}

// ---------------------------------------------------------------- K_MAIN
// 256 blocks x 512 thr. Per block: 32 query rows x 576 cols, BK=64, 8 chunks.
// B chunk (73,728 B) + A chunk (4 KB) staged via global_load_lds width=16;
// XOR-swizzled layouts give conflict-free b128 frag reads. qn in registers.
__global__ __launch_bounds__(512, 2) void k_main(
    const bf16_t* __restrict__ Aq, const bf16_t* __restrict__ Bsw,
    const float* __restrict__ bias, const float* __restrict__ ph,
    float* __restrict__ out)
{
    __shared__ bf16_t Bb[36864];   // 576 x 64 elems (73,728 B)
    __shared__ bf16_t Ab[2048];    //  32 x 64 elems ( 4,096 B)
    __shared__ float qln[4][32];
    __shared__ float phs[NWAY];

    const int t = threadIdx.x, bm = blockIdx.x;
    if (t < NWAY) phs[t] = ph[t];

    const int l = t & 63, w = t >> 6;
    const int wm = w & 1, wn = w >> 1;
    const int r15 = l & 15, quad = l >> 4;

    // swizzled frag offsets (elems); row&7 == r15&7 for all our rows/tiles
    const int xt0 = ((quad ^ (r15 & 7)) * 8);         // ksub=0: k-seg = quad
    const int xt1 = (((4 + quad) ^ (r15 & 7)) * 8);   // ksub=1: k-seg = 4+quad
    const int aoff = (wm * 16 + r15) * 64;
    const int boff = (wn * 144 + r15) * 64;           // + tt*1024 + xt

    const bf16_t* gA = Aq + (size_t)bm * 16384;

    f32x4 acc[9];
#pragma unroll
    for (int i = 0; i < 9; ++i) acc[i] = (f32x4){0.f, 0.f, 0.f, 0.f};

    for (int ck = 0; ck < 8; ++ck) {
        if (ck) __syncthreads();          // WAR guard on LDS reuse
        // ---- stage: 9 B-insts/wave + 1 A-inst on waves 0..3 (1 KB per inst)
        {
            const int wb = w * 4608 + l * 8;          // elems
#pragma unroll
            for (int i = 0; i < 9; ++i) {
                const int off = wb + i * 512;
                ld16(Bsw + (size_t)ck * 36864 + off, Bb + off);
            }
            if (w < 4) {
                const int off = w * 512 + l * 8;
                ld16(gA + ck * 2048 + off, Ab + off);
            }
        }
        __syncthreads();

        bf16x8_t a0 = *(const bf16x8_t*)(Ab + aoff + xt0);
        bf16x8_t a1 = *(const bf16x8_t*)(Ab + aoff + xt1);
#pragma unroll
        for (int tt = 0; tt < 9; ++tt) {
            bf16x8_t b0 = *(const bf16x8_t*)(Bb + boff + tt * 1024 + xt0);
            bf16x8_t b1 = *(const bf16x8_t*)(Bb + boff + tt * 1024 + xt1);
            acc[tt] = __builtin_amdgcn_mfma_f32_16x16x32_bf16(a0, b0, acc[tt], 0, 0, 0);
            acc[tt] = __builtin_amdgcn_mfma_f32_16x16x32_bf16(a1, b1, acc[tt], 0, 0, 0);
        }
    }

    // ---- qn = sum over this wave's W-cols of (e + bias)^2 ----
    const int nW = (wn == 3) ? 5 : 9;     // wn==3: tiles 0..4 are W, 5..8 are G
    float qp[4] = {0.f, 0.f, 0.f, 0.f};
    for (int tt = 0; tt < nW; ++tt) {
        float bv = bias[wn * 144 + tt * 16 + r15];
#pragma unroll
        for (int reg = 0; reg < 4; ++reg) {
            float v = acc[tt][reg] + bv;
            qp[reg] += v * v;
        }
    }
#pragma unroll
    for (int reg = 0; reg < 4; ++reg) {
        float s = qp[reg];
        s += __shfl_xor(s, 1); s += __shfl_xor(s, 2);
        s += __shfl_xor(s, 4); s += __shfl_xor(s, 8);
        if (r15 == 0) qln[wn][wm * 16 + quad * 4 + reg] = s;
    }
    __syncthreads();

    // ---- wn==3 waves write dists: qt + ph[c] - 2 * (q.G_c) ----
    if (wn == 3) {
#pragma unroll
        for (int reg = 0; reg < 4; ++reg) {
            const int row_local = quad * 4 + reg;
            const float qt = qln[0][wm * 16 + row_local] + qln[1][wm * 16 + row_local] +
                             qln[2][wm * 16 + row_local] + qln[3][wm * 16 + row_local];
            const int rowg = bm * 32 + wm * 16 + row_local;
#pragma unroll
            for (int tg = 0; tg < 4; ++tg) {
                const int c = tg * 16 + r15;
                out[(size_t)rowg * NWAY + c] = qt + phs[c] - 2.0f * acc[5 + tg][reg];
            }
        }
    }
}

// ---------------------------------------------------------------- launch
extern "C" void kernel_launch(void* const* d_in, const int* in_sizes, int n_in,
                              void* d_out, int out_size, void* d_ws, size_t ws_size,
                              hipStream_t stream)
{
    const float* support = (const float*)d_in[0];
    const float* query   = (const float*)d_in[1];
    const float* W       = (const float*)d_in[2];
    const float* bias    = (const float*)d_in[3];
    float* out = (float*)d_out;

    char* ws = (char*)d_ws;
    bf16_t* Aq  = (bf16_t*)ws;                         // 8,388,608 B
    bf16_t* Bsw = (bf16_t*)(ws + 8388608);             //   589,824 B
    float*  ph  = (float*)(ws + 8388608 + 589824);     //       256 B

    k_prep<<<1344, 256, 0, stream>>>(support, query, W, bias, Aq, Bsw, ph);
    k_main<<<256, 512, 0, stream>>>(Aq, Bsw, bias, ph, out);
}

// Round 6
// 125.797 us; speedup vs baseline: 1.2534x; 1.2534x over previous
//
#include <hip/hip_runtime.h>
#include <hip/hip_bf16.h>

#define D 512
#define NWAY 64
#define KSHOT 16
#define NQ 8192

typedef __bf16 bf16_t;
typedef __bf16 bf16x8_t __attribute__((ext_vector_type(8)));
typedef float  f32x4    __attribute__((ext_vector_type(4)));

typedef __attribute__((address_space(1))) const void gv_t;
typedef __attribute__((address_space(3))) void lv_t;
__device__ __forceinline__ void ld16(const void* g, void* l) {
    __builtin_amdgcn_global_load_lds((gv_t*)g, (lv_t*)l, 16, 0, 0);
}

// Global pre-swizzled layouts (bf16 elems; 8-elem = 16 B segments):
//  Aq: [rt(256)][ck(8)][m(32)][seg(8)]  off = rt*16384 + ck*2048 + m*64 + ((s^(m&7))*8)
//  Bsw:[ck(8)][n(576)][seg(8)]          off = ck*36864 + n*64 + ((s^(n&7))*8)
//      rows 0..511 = W, rows 512..575 = G_c = W^T p_c

// ---------------------------------------------------------------- K_PREP1
// b<64: class chain cm->P->ph (+P to global) | 64..1087: query->bf16 swz
// | 1088..1215: W->bf16 swz
__global__ __launch_bounds__(256) void k_prep1(
    const float* __restrict__ sup, const float* __restrict__ query,
    const float* __restrict__ W,   const float* __restrict__ bias,
    bf16_t* __restrict__ Aq, bf16_t* __restrict__ Bsw,
    float* __restrict__ Pg, float* __restrict__ ph)
{
    const int b = blockIdx.x, t = threadIdx.x;

    if (b < 64) {                         // ---- class chain (critical path, dispatch first)
        const int c = b;
        __shared__ __align__(16) float cm[D];
        __shared__ __align__(16) float P[D];
        __shared__ float red[4];

        {   // cm_c = mean over shots
            const int d = t * 2;
            float sx = 0.f, sy = 0.f;
#pragma unroll
            for (int j = 0; j < KSHOT; ++j) {
                float2 v = *(const float2*)(sup + (size_t)(c * KSHOT + j) * D + d);
                sx += v.x; sy += v.y;
            }
            cm[d] = sx * (1.0f / KSHOT); cm[d + 1] = sy * (1.0f / KSHOT);
        }
        __syncthreads();

        {   // P_c[j] = cm . W_j + b_j  -> LDS + global
#pragma unroll
            for (int h = 0; h < 2; ++h) {
                const int j = t + h * 256;
                const f32x4* wr = (const f32x4*)(W + (size_t)j * D);
                const f32x4* cr = (const f32x4*)cm;
                float s = 0.f;
#pragma unroll 8
                for (int i = 0; i < 128; ++i) {
                    f32x4 a = cr[i], wv = wr[i];
                    s += a[0]*wv[0] + a[1]*wv[1] + a[2]*wv[2] + a[3]*wv[3];
                }
                const float val = s + bias[j];
                P[j] = val;
                Pg[(size_t)c * D + j] = val;
            }
        }
        __syncthreads();

        {   // ph_c = ||p||^2 - 2 b.p
            float pp = 0.f;
#pragma unroll
            for (int h = 0; h < 2; ++h) {
                const int j = t + h * 256;
                float v = P[j];
                pp += v * v - 2.0f * bias[j] * v;
            }
#pragma unroll
            for (int off = 32; off; off >>= 1) pp += __shfl_xor(pp, off);
            if ((t & 63) == 0) red[t >> 6] = pp;
            __syncthreads();
            if (t == 0) ph[c] = red[0] + red[1] + red[2] + red[3];
        }
        return;
    }

    if (b < 1088) {                       // ---- query conversion, 8 rows/block
        const int r  = (b - 64) * 8 + (t >> 5);
        const int m  = r & 31, rt = r >> 5;
        const int s2 = t & 31;
#pragma unroll
        for (int h = 0; h < 2; ++h) {
            const int sl = s2 + h * 32;
            const f32x4* qp = (const f32x4*)(query + (size_t)r * D + sl * 8);
            f32x4 v0 = qp[0], v1 = qp[1];
            bf16x8_t hv = { (bf16_t)v0[0], (bf16_t)v0[1], (bf16_t)v0[2], (bf16_t)v0[3],
                            (bf16_t)v1[0], (bf16_t)v1[1], (bf16_t)v1[2], (bf16_t)v1[3] };
            const int ck = sl >> 3, s = sl & 7;
            *(bf16x8_t*)(Aq + (size_t)rt * 16384 + ck * 2048 + m * 64 + ((s ^ (m & 7)) * 8)) = hv;
        }
        return;
    }

    {                                     // ---- W conversion, 4 rows/block
        const int n = (b - 1088) * 4 + (t >> 6);
        const int sl = t & 63;
        const f32x4* wp = (const f32x4*)(W + (size_t)n * D + sl * 8);
        f32x4 v0 = wp[0], v1 = wp[1];
        bf16x8_t hv = { (bf16_t)v0[0], (bf16_t)v0[1], (bf16_t)v0[2], (bf16_t)v0[3],
                        (bf16_t)v1[0], (bf16_t)v1[1], (bf16_t)v1[2], (bf16_t)v1[3] };
        const int ck = sl >> 3, s = sl & 7;
        *(bf16x8_t*)(Bsw + (size_t)ck * 36864 + n * 64 + ((s ^ (n & 7)) * 8)) = hv;
    }
}

// ---------------------------------------------------------------- K_PREP2
// G_c[k] = sum_j P_c[j] W[j][k] -> Bsw rows 512+c (swizzled bf16).
// grid 256 = 64 classes x 4 k-chunks of 128; lanes cover consecutive k
// (coalesced W reads), j split x2 across thread halves, LDS combine.
__global__ __launch_bounds__(256) void k_prep2(
    const float* __restrict__ Pg, const float* __restrict__ W,
    bf16_t* __restrict__ Bsw)
{
    __shared__ __align__(16) float Pl[D];
    __shared__ float sG[2][128];

    const int c = blockIdx.x >> 2, kc = blockIdx.x & 3;
    const int t = threadIdx.x;
    const int kl = t & 127, jh = t >> 7;
    const int k = kc * 128 + kl;

    ((float2*)Pl)[t] = ((const float2*)(Pg + (size_t)c * D))[t];
    __syncthreads();

    float g = 0.f;
    const float* wcol = W + (size_t)jh * 256 * D + k;
#pragma unroll 8
    for (int j = 0; j < 256; ++j)
        g += Pl[jh * 256 + j] * wcol[(size_t)j * D];
    sG[jh][kl] = g;
    __syncthreads();

    if (jh == 0) {
        const float gt = sG[0][kl] + sG[1][kl];
        const int n = 512 + c;
        const int ck = k >> 6, s = (k >> 3) & 7, e = k & 7;
        Bsw[(size_t)ck * 36864 + n * 64 + ((s ^ (c & 7)) * 8) + e] = (bf16_t)gt;
    }
}

// ---------------------------------------------------------------- K_MAIN
// 256 blocks x 512 thr. 32 query rows x 576 cols, BK=64, 8 chunks via
// global_load_lds(16B); XOR-swizzled conflict-free frag reads; qn in regs.
// qn mask loop has CONSTANT bound 9 (acc stays in registers — R5's scratch bug).
__global__ __launch_bounds__(512, 2) void k_main(
    const bf16_t* __restrict__ Aq, const bf16_t* __restrict__ Bsw,
    const float* __restrict__ bias, const float* __restrict__ ph,
    float* __restrict__ out)
{
    __shared__ bf16_t Bb[36864];   // 73,728 B
    __shared__ bf16_t Ab[2048];    //  4,096 B
    __shared__ float qln[4][32];
    __shared__ float phs[NWAY];
    __shared__ float bs[576];      // zero-padded bias

    const int t = threadIdx.x, bm = blockIdx.x;
    if (t < 512) bs[t] = bias[t];
    if (t < NWAY) { bs[512 + t] = 0.f; phs[t] = ph[t]; }

    const int l = t & 63, w = t >> 6;
    const int wm = w & 1, wn = w >> 1;
    const int r15 = l & 15, quad = l >> 4;

    const int xt0 = ((quad ^ (r15 & 7)) * 8);
    const int xt1 = (((4 + quad) ^ (r15 & 7)) * 8);
    const int aoff = (wm * 16 + r15) * 64;
    const int boff = (wn * 144 + r15) * 64;

    const bf16_t* gA = Aq + (size_t)bm * 16384;

    f32x4 acc[9];
#pragma unroll
    for (int i = 0; i < 9; ++i) acc[i] = (f32x4){0.f, 0.f, 0.f, 0.f};

    for (int ck = 0; ck < 8; ++ck) {
        if (ck) __syncthreads();          // WAR guard on LDS reuse
        {
            const int wb = w * 4608 + l * 8;
#pragma unroll
            for (int i = 0; i < 9; ++i) {
                const int off = wb + i * 512;
                ld16(Bsw + (size_t)ck * 36864 + off, Bb + off);
            }
            if (w < 4) {
                const int off = w * 512 + l * 8;
                ld16(gA + ck * 2048 + off, Ab + off);
            }
        }
        __syncthreads();

        bf16x8_t a0 = *(const bf16x8_t*)(Ab + aoff + xt0);
        bf16x8_t a1 = *(const bf16x8_t*)(Ab + aoff + xt1);
#pragma unroll
        for (int tt = 0; tt < 9; ++tt) {
            bf16x8_t b0 = *(const bf16x8_t*)(Bb + boff + tt * 1024 + xt0);
            bf16x8_t b1 = *(const bf16x8_t*)(Bb + boff + tt * 1024 + xt1);
            acc[tt] = __builtin_amdgcn_mfma_f32_16x16x32_bf16(a0, b0, acc[tt], 0, 0, 0);
            acc[tt] = __builtin_amdgcn_mfma_f32_16x16x32_bf16(a1, b1, acc[tt], 0, 0, 0);
        }
    }

    // ---- qn = sum over W-cols of (e + bias)^2 ; constant-bound, masked ----
    float qp[4] = {0.f, 0.f, 0.f, 0.f};
#pragma unroll
    for (int tt = 0; tt < 9; ++tt) {
        const int colbase = wn * 144 + tt * 16;
        const float m = (colbase < 512) ? 1.f : 0.f;   // wave-uniform
        const float bv = bs[colbase + r15];            // LDS, zero-padded
#pragma unroll
        for (int reg = 0; reg < 4; ++reg) {
            float v = acc[tt][reg] + bv;
            qp[reg] += m * v * v;
        }
    }
#pragma unroll
    for (int reg = 0; reg < 4; ++reg) {
        float s = qp[reg];
        s += __shfl_xor(s, 1); s += __shfl_xor(s, 2);
        s += __shfl_xor(s, 4); s += __shfl_xor(s, 8);
        if (r15 == 0) qln[wn][wm * 16 + quad * 4 + reg] = s;
    }
    __syncthreads();

    // ---- wn==3 waves write dists: qt + ph[c] - 2 * (q.G_c) ----
    if (wn == 3) {
#pragma unroll
        for (int reg = 0; reg < 4; ++reg) {
            const int row_local = quad * 4 + reg;
            const float qt = qln[0][wm * 16 + row_local] + qln[1][wm * 16 + row_local] +
                             qln[2][wm * 16 + row_local] + qln[3][wm * 16 + row_local];
            const int rowg = bm * 32 + wm * 16 + row_local;
#pragma unroll
            for (int tg = 0; tg < 4; ++tg) {
                const int c = tg * 16 + r15;
                out[(size_t)rowg * NWAY + c] = qt + phs[c] - 2.0f * acc[5 + tg][reg];
            }
        }
    }
}

// ---------------------------------------------------------------- launch
extern "C" void kernel_launch(void* const* d_in, const int* in_sizes, int n_in,
                              void* d_out, int out_size, void* d_ws, size_t ws_size,
                              hipStream_t stream)
{
    const float* support = (const float*)d_in[0];
    const float* query   = (const float*)d_in[1];
    const float* W       = (const float*)d_in[2];
    const float* bias    = (const float*)d_in[3];
    float* out = (float*)d_out;

    char* ws = (char*)d_ws;
    bf16_t* Aq  = (bf16_t*)ws;                          // 8,388,608 B
    bf16_t* Bsw = (bf16_t*)(ws + 8388608);              //   589,824 B
    float*  ph  = (float*)(ws + 8388608 + 589824);      //       256 B
    float*  Pg  = (float*)(ws + 8388608 + 589824 + 256);//   131,072 B

    k_prep1<<<1216, 256, 0, stream>>>(support, query, W, bias, Aq, Bsw, Pg, ph);
    k_prep2<<<256, 256, 0, stream>>>(Pg, W, Bsw);
    k_main<<<256, 512, 0, stream>>>(Aq, Bsw, bias, ph, out);
}

// Round 7
// 110.832 us; speedup vs baseline: 1.4227x; 1.1350x over previous
//
#include <hip/hip_runtime.h>
#include <hip/hip_bf16.h>

#define D 512
#define NWAY 64
#define KSHOT 16
#define NQ 8192

typedef __bf16 bf16_t;
typedef __bf16 bf16x8_t __attribute__((ext_vector_type(8)));
typedef float  f32x4    __attribute__((ext_vector_type(4)));

typedef __attribute__((address_space(1))) const void gv_t;
typedef __attribute__((address_space(3))) void lv_t;
__device__ __forceinline__ void ld16(const void* g, void* l) {
    __builtin_amdgcn_global_load_lds((gv_t*)g, (lv_t*)l, 16, 0, 0);
}

// Bsw: [ck(8)][n(576)][seg(8)] bf16, off = ck*36864 + n*64 + ((s^(n&7))*8)
//   rows 0..511 = W (bf16), rows 512..575 = G_c = W^T p_c

// ---------------------------------------------------------------- K_PREP1
// b<256: P[c][jq*128..+128] = cm_c . W_j + b_j  (cm recomputed per block, cheap)
// b>=256 (128 blocks): W -> bf16 swizzled into Bsw rows 0..511
__global__ __launch_bounds__(256) void k_prep1(
    const float* __restrict__ sup, const float* __restrict__ W,
    const float* __restrict__ bias, float* __restrict__ Pg,
    bf16_t* __restrict__ Bsw)
{
    const int b = blockIdx.x, t = threadIdx.x;

    if (b < 256) {                         // ---- P blocks
        const int c = b >> 2, jq = b & 3;
        __shared__ __align__(16) float cm[D];
        {   // cm_c = mean over shots (float2 per thread)
            const int d = t * 2;
            float sx = 0.f, sy = 0.f;
#pragma unroll
            for (int j = 0; j < KSHOT; ++j) {
                float2 v = *(const float2*)(sup + (size_t)(c * KSHOT + j) * D + d);
                sx += v.x; sy += v.y;
            }
            cm[d] = sx * (1.0f / KSHOT); cm[d + 1] = sy * (1.0f / KSHOT);
        }
        __syncthreads();
        // P: 128 j per block, each j split over 2 lanes (256-dim half-dots)
        const int j = jq * 128 + (t >> 1);
        const int half = t & 1;
        const f32x4* wr = (const f32x4*)(W + (size_t)j * D + half * 256);
        const f32x4* cr = (const f32x4*)(cm + half * 256);
        float s = 0.f;
#pragma unroll 8
        for (int i = 0; i < 64; ++i) {
            f32x4 a = cr[i], wv = wr[i];
            s += a[0]*wv[0] + a[1]*wv[1] + a[2]*wv[2] + a[3]*wv[3];
        }
        s += __shfl_xor(s, 1);
        if (!half) Pg[(size_t)c * D + j] = s + bias[j];
        return;
    }

    {                                      // ---- W conversion, 4 rows/block
        const int n = (b - 256) * 4 + (t >> 6);
        const int sl = t & 63;
        const f32x4* wp = (const f32x4*)(W + (size_t)n * D + sl * 8);
        f32x4 v0 = wp[0], v1 = wp[1];
        bf16x8_t hv = { (bf16_t)v0[0], (bf16_t)v0[1], (bf16_t)v0[2], (bf16_t)v0[3],
                        (bf16_t)v1[0], (bf16_t)v1[1], (bf16_t)v1[2], (bf16_t)v1[3] };
        const int ck = sl >> 3, s = sl & 7;
        *(bf16x8_t*)(Bsw + (size_t)ck * 36864 + n * 64 + ((s ^ (n & 7)) * 8)) = hv;
    }
}

// ---------------------------------------------------------------- K_PREP2
// 256 blocks: G_c[kq*128..+128] -> Bsw rows 512+c (swizzled bf16);
// kq==0 blocks also reduce ph_c = ||p||^2 - 2 b.p
__global__ __launch_bounds__(256) void k_prep2(
    const float* __restrict__ Pg, const float* __restrict__ W,
    const float* __restrict__ bias, bf16_t* __restrict__ Bsw,
    float* __restrict__ ph)
{
    __shared__ __align__(16) float Pl[D];
    __shared__ float sG[2][128];
    __shared__ float red[4];

    const int c = blockIdx.x >> 2, kc = blockIdx.x & 3;
    const int t = threadIdx.x;
    const int kl = t & 127, jh = t >> 7;
    const int k = kc * 128 + kl;

    ((float2*)Pl)[t] = ((const float2*)(Pg + (size_t)c * D))[t];
    __syncthreads();

    float g = 0.f;
    const float* wcol = W + (size_t)jh * 256 * D + k;
#pragma unroll 8
    for (int j = 0; j < 256; ++j)
        g += Pl[jh * 256 + j] * wcol[(size_t)j * D];
    sG[jh][kl] = g;

    if (kc == 0) {
        float v1 = Pl[t], v2 = Pl[t + 256];
        float pp = v1 * v1 - 2.0f * bias[t] * v1 + v2 * v2 - 2.0f * bias[t + 256] * v2;
#pragma unroll
        for (int off = 32; off; off >>= 1) pp += __shfl_xor(pp, off);
        if ((t & 63) == 0) red[t >> 6] = pp;
    }
    __syncthreads();

    if (jh == 0) {
        const float gt = sG[0][kl] + sG[1][kl];
        const int n = 512 + c;
        const int ck = k >> 6, s = (k >> 3) & 7, e = k & 7;
        Bsw[(size_t)ck * 36864 + n * 64 + ((s ^ (c & 7)) * 8) + e] = (bf16_t)gt;
    }
    if (kc == 0 && t == 0) ph[c] = red[0] + red[1] + red[2] + red[3];
}

// ---------------------------------------------------------------- K_MAIN
// 256 blocks x 512 thr, 2 blocks/CU. Per chunk (BK=64, 8 chunks):
// waves 0..3 stage the 32x64 fp32 query chunk -> swizzled bf16 LDS (in-reg cvt);
// all waves stage B chunk (72 KB) via global_load_lds(16B). Conflict-free
// b128 frag reads; qn in registers (constant-bound mask loop).
__global__ __launch_bounds__(512, 2) void k_main(
    const float* __restrict__ query, const bf16_t* __restrict__ Bsw,
    const float* __restrict__ bias, const float* __restrict__ ph,
    float* __restrict__ out)
{
    __shared__ bf16_t Bb[36864];   // 73,728 B
    __shared__ bf16_t Ab[2048];    //  4,096 B
    __shared__ float qln[4][32];   //    512 B
    __shared__ float phs[NWAY];    //    256 B
    __shared__ float bs[576];      //  2,304 B   (total 80,896 B -> 2 blocks/CU)

    const int t = threadIdx.x, bm = blockIdx.x;
    bs[t < 512 ? t : 511] = bias[t < 512 ? t : 511];
    if (t < NWAY) { bs[512 + t] = 0.f; phs[t] = ph[t]; }

    const int l = t & 63, w = t >> 6;
    const int wm = w & 1, wn = w >> 1;
    const int r15 = l & 15, quad = l >> 4;

    const int xt0 = ((quad ^ (r15 & 7)) * 8);
    const int xt1 = (((4 + quad) ^ (r15 & 7)) * 8);
    const int aoff = (wm * 16 + r15) * 64;
    const int boff = (wn * 144 + r15) * 64;

    // A-staging coords (waves 0..3: 32 rows x 8 segs)
    const int am = (w * 64 + l) >> 3;     // 0..31 (valid when w<4)
    const int as = l & 7;
    const float* aq = query + (size_t)(bm * 32 + am) * D + as * 8;
    bf16_t* adst = Ab + am * 64 + ((as ^ (am & 7)) * 8);

    f32x4 acc[9];
#pragma unroll
    for (int i = 0; i < 9; ++i) acc[i] = (f32x4){0.f, 0.f, 0.f, 0.f};

    for (int ck = 0; ck < 8; ++ck) {
        if (ck) __syncthreads();          // WAR guard on LDS reuse
        if (w < 4) {                      // stage A chunk: fp32 -> bf16 swizzled
            f32x4 v0 = *(const f32x4*)(aq + ck * 64);
            f32x4 v1 = *(const f32x4*)(aq + ck * 64 + 4);
            bf16x8_t hv = { (bf16_t)v0[0], (bf16_t)v0[1], (bf16_t)v0[2], (bf16_t)v0[3],
                            (bf16_t)v1[0], (bf16_t)v1[1], (bf16_t)v1[2], (bf16_t)v1[3] };
            *(bf16x8_t*)adst = hv;
        }
        {                                 // stage B chunk via async DMA
            const int wb = w * 4608 + l * 8;
#pragma unroll
            for (int i = 0; i < 9; ++i) {
                const int off = wb + i * 512;
                ld16(Bsw + (size_t)ck * 36864 + off, Bb + off);
            }
        }
        __syncthreads();

        bf16x8_t a0 = *(const bf16x8_t*)(Ab + aoff + xt0);
        bf16x8_t a1 = *(const bf16x8_t*)(Ab + aoff + xt1);
#pragma unroll
        for (int tt = 0; tt < 9; ++tt) {
            bf16x8_t b0 = *(const bf16x8_t*)(Bb + boff + tt * 1024 + xt0);
            bf16x8_t b1 = *(const bf16x8_t*)(Bb + boff + tt * 1024 + xt1);
            acc[tt] = __builtin_amdgcn_mfma_f32_16x16x32_bf16(a0, b0, acc[tt], 0, 0, 0);
            acc[tt] = __builtin_amdgcn_mfma_f32_16x16x32_bf16(a1, b1, acc[tt], 0, 0, 0);
        }
    }

    // ---- qn = sum over W-cols of (e + bias)^2 ; constant bound, masked ----
    float qp[4] = {0.f, 0.f, 0.f, 0.f};
#pragma unroll
    for (int tt = 0; tt < 9; ++tt) {
        const int colbase = wn * 144 + tt * 16;
        const float m = (colbase < 512) ? 1.f : 0.f;   // wave-uniform
        const float bv = bs[colbase + r15];
#pragma unroll
        for (int reg = 0; reg < 4; ++reg) {
            float v = acc[tt][reg] + bv;
            qp[reg] += m * v * v;
        }
    }
#pragma unroll
    for (int reg = 0; reg < 4; ++reg) {
        float s = qp[reg];
        s += __shfl_xor(s, 1); s += __shfl_xor(s, 2);
        s += __shfl_xor(s, 4); s += __shfl_xor(s, 8);
        if (r15 == 0) qln[wn][wm * 16 + quad * 4 + reg] = s;
    }
    __syncthreads();

    // ---- wn==3 waves write dists: qt + ph[c] - 2 * (q.G_c) ----
    if (wn == 3) {
#pragma unroll
        for (int reg = 0; reg < 4; ++reg) {
            const int row_local = quad * 4 + reg;
            const float qt = qln[0][wm * 16 + row_local] + qln[1][wm * 16 + row_local] +
                             qln[2][wm * 16 + row_local] + qln[3][wm * 16 + row_local];
            const int rowg = bm * 32 + wm * 16 + row_local;
#pragma unroll
            for (int tg = 0; tg < 4; ++tg) {
                const int c = tg * 16 + r15;
                out[(size_t)rowg * NWAY + c] = qt + phs[c] - 2.0f * acc[5 + tg][reg];
            }
        }
    }
}

// ---------------------------------------------------------------- launch
extern "C" void kernel_launch(void* const* d_in, const int* in_sizes, int n_in,
                              void* d_out, int out_size, void* d_ws, size_t ws_size,
                              hipStream_t stream)
{
    const float* support = (const float*)d_in[0];
    const float* query   = (const float*)d_in[1];
    const float* W       = (const float*)d_in[2];
    const float* bias    = (const float*)d_in[3];
    float* out = (float*)d_out;

    char* ws = (char*)d_ws;
    bf16_t* Bsw = (bf16_t*)ws;                    // 589,824 B
    float*  ph  = (float*)(ws + 589824);          //     256 B
    float*  Pg  = (float*)(ws + 589824 + 256);    // 131,072 B

    k_prep1<<<384, 256, 0, stream>>>(support, W, bias, Pg, Bsw);
    k_prep2<<<256, 256, 0, stream>>>(Pg, W, bias, Bsw, ph);
    k_main<<<256, 512, 0, stream>>>(query, Bsw, bias, ph, out);
}